// Round 18
// baseline (238.434 us; speedup 1.0000x reference)
//
#include <hip/hip_runtime.h>
#include <cfloat>

// Geometry: z (32,256,32,32) f32, W (1024,256) f32.
// P = 32768 (p = n*1024+hw), K = 256, CODES = 1024.
// d_out = [quantized 8388608][straight_through 8388608][indices-as-float 32768]
// Strategy: bf16 MFMA screen + viability filter + exact fp32 rescore of
// viable candidates (bitwise-identical chain). Screen v8: B fragments read
// DIRECTLY from L2-resident whi (512KB) into registers — no LDS staging, no
// double-buffer, zero in-loop barriers (R12's LDS path was bank-conflict
// bound: measured 16 conflict-cyc per ds_read_b128 across all variants).

#define P_TOTAL   32768
#define N_CODES   1024
#define Q_ELEMS   8388608
#define EPS_SCREEN 4.0e-3f   // rigorous bf16-screen bound B~1.1e-3; EPS > 2B
#define CAND_CAP  64

typedef __attribute__((ext_vector_type(8))) short bf16x8;
typedef __attribute__((ext_vector_type(4))) float f32x4;

__device__ __forceinline__ unsigned short f2bf(float f) {   // RN-even f32->bf16
    unsigned u = __builtin_bit_cast(unsigned, f);
    u += 0x7FFF + ((u >> 16) & 1);
    return (unsigned short)(u >> 16);
}

__device__ __forceinline__ float sq_sep(float v) {
    float t = v * v;
    asm volatile("" : "+v"(t));
    return t;
}

// ---------------------------------------------------------------------------
// k0t: W[1024][256] -> Wtf[256][1024] f32 (exact copy; validated R2/R10).
// ---------------------------------------------------------------------------
__global__ void k0t_transpose(const float* __restrict__ wemb, float* __restrict__ wt) {
    __shared__ float tile[64 * 65];
    const int tid = threadIdx.x;
    const int ct = blockIdx.x >> 2, kt = blockIdx.x & 3;
    const int c0 = ct * 64, k0 = kt * 64;
    const int rr = tid >> 4, cg = tid & 15;
    #pragma unroll
    for (int i = 0; i < 4; ++i) {
        const int row = i * 16 + rr;
        const float4 v = *(const float4*)&wemb[(size_t)(c0 + row) * 256 + k0 + cg * 4];
        tile[row * 65 + cg * 4 + 0] = v.x;
        tile[row * 65 + cg * 4 + 1] = v.y;
        tile[row * 65 + cg * 4 + 2] = v.z;
        tile[row * 65 + cg * 4 + 3] = v.w;
    }
    __syncthreads();
    #pragma unroll
    for (int i = 0; i < 4; ++i) {
        const int krow = i * 16 + rr;
        float4 v;
        v.x = tile[(cg * 4 + 0) * 65 + krow];
        v.y = tile[(cg * 4 + 1) * 65 + krow];
        v.z = tile[(cg * 4 + 2) * 65 + krow];
        v.w = tile[(cg * 4 + 3) * 65 + krow];
        *(float4*)&wt[(size_t)(k0 + krow) * 1024 + c0 + cg * 4] = v;
    }
}

// ---------------------------------------------------------------------------
// k0w: W -> W_hi bf16, LINEAR layout (no swizzle: k2s v8 reads from global,
// no LDS bank concerns; k2s is the only consumer).
// ---------------------------------------------------------------------------
__global__ void k0w_pack(const float* __restrict__ wemb, unsigned short* __restrict__ whi) {
    const int t = blockIdx.x * 256 + threadIdx.x;   // 32768 granules
    const int c = t >> 5, g = t & 31;
    const float4 v0 = *(const float4*)&wemb[(size_t)c * 256 + g * 8];
    const float4 v1 = *(const float4*)&wemb[(size_t)c * 256 + g * 8 + 4];
    bf16x8 hv;
    hv[0] = (short)f2bf(v0.x); hv[1] = (short)f2bf(v0.y);
    hv[2] = (short)f2bf(v0.z); hv[3] = (short)f2bf(v0.w);
    hv[4] = (short)f2bf(v1.x); hv[5] = (short)f2bf(v1.y);
    hv[6] = (short)f2bf(v1.z); hv[7] = (short)f2bf(v1.w);
    *(bf16x8*)(whi + (size_t)c * 256 + g * 8) = hv;
}

// ---------------------------------------------------------------------------
// k0z: z [n][k][hw] f32 -> z_hi [p][k] bf16 (transpose via LDS). grid 512.
// ---------------------------------------------------------------------------
#define T16S 280   // ushort stride: 560B rows (16B aligned)
__global__ void k0z_pack(const float* __restrict__ z, unsigned short* __restrict__ zhi) {
    __shared__ unsigned short t16[64 * T16S];   // 35,840 B
    const int tid = threadIdx.x;
    const int n = blockIdx.x >> 4, hc = blockIdx.x & 15;
    const int hw0 = hc * 64;
    const int w = tid >> 6, hl = tid & 63;
    #pragma unroll
    for (int i = 0; i < 64; ++i) {
        const int k = i * 4 + w;
        const float v = z[((size_t)(n * 256 + k) << 10) + hw0 + hl];
        t16[hl * T16S + k] = f2bf(v);
    }
    __syncthreads();
    const int row = tid >> 2, cp = tid & 3;
    const size_t p0 = (size_t)(n * 1024 + hw0);
    #pragma unroll
    for (int i = 0; i < 8; ++i) {
        const int chunk = i * 4 + cp;
        *(bf16x8*)(zhi + (p0 + row) * 256 + chunk * 8) =
            *(const bf16x8*)&t16[row * T16S + chunk * 8];
    }
}

// ---------------------------------------------------------------------------
// k1: blocks 0-3: wsq[c] (numpy pairwise order). blocks 4-131: zero candCnt.
// ---------------------------------------------------------------------------
__global__ void k1_wsq(const float* __restrict__ wemb, float* __restrict__ wsq,
                       int* __restrict__ candCnt) {
    const int b = blockIdx.x, tid = threadIdx.x;
    if (b >= 4) { candCnt[(b - 4) * 256 + tid] = 0; return; }
    const int c = b * 256 + tid;
    const float* base = wemb + (size_t)c * 256;
    float half[2];
    #pragma unroll
    for (int h = 0; h < 2; ++h) {
        const float* x = base + h * 128;
        float r[8];
        #pragma unroll
        for (int j = 0; j < 8; ++j) r[j] = sq_sep(x[j]);
        for (int i = 8; i < 128; i += 8) {
            #pragma unroll
            for (int j = 0; j < 8; ++j) r[j] += sq_sep(x[i + j]);
        }
        half[h] = ((r[0] + r[1]) + (r[2] + r[3])) + ((r[4] + r[5]) + (r[6] + r[7]));
    }
    wsq[c] = half[0] + half[1];
}

// ---------------------------------------------------------------------------
// k2s v8: bf16 MFMA screen, B from GLOBAL (L2-resident whi, 512KB).
// Block = 64 pos x 512 codes (half), 16 chunks of 32 codes; grid 1024.
// Per ks: 2 global_load_dwordx4 (per-lane base + imm offsets) -> 2 MFMAs.
// No Bs LDS, no double-buffer, NO in-loop barriers: waves free-run; L2
// latency hidden by 16 waves/CU + compiler load-ahead. Fragment mapping and
// collect semantics identical to validated R12 (values bit-identical:
// same bf16 data, different memory path).
// ---------------------------------------------------------------------------
__launch_bounds__(256)
__global__ void k2s_screen(const unsigned short* __restrict__ zhi,
                           const unsigned short* __restrict__ whi,
                           const float* __restrict__ wsq,
                           unsigned short* __restrict__ candC,
                           float* __restrict__ candD,
                           int* __restrict__ candCnt) {
    __shared__ float wsqs[512];                  // this half's norms
    const int tid = threadIdx.x, bid = blockIdx.x;
    const int pgrp = bid >> 1, half = bid & 1;
    const int w = tid >> 6, l = tid & 63;
    const int la = l & 15, kg = l >> 4;
    const int m0 = pgrp * 64 + w * 16;
    const int cb0 = half * 512;

    wsqs[tid]       = wsq[cb0 + tid];
    wsqs[tid + 256] = wsq[cb0 + tid + 256];

    bf16x8 af[8];
    #pragma unroll
    for (int ks = 0; ks < 8; ++ks)
        af[ks] = *(const bf16x8*)(zhi + (size_t)(m0 + la) * 256 + ks * 32 + kg * 8);

    float rg[4];
    #pragma unroll
    for (int r = 0; r < 4; ++r) rg[r] = FLT_MAX;

    __syncthreads();                      // wsqs ready (only barrier)

    // per-lane B base: row (cb0+la), k-column kg*8 (ushort units)
    const unsigned short* wbase = whi + ((size_t)(cb0 + la) << 8) + kg * 8;

    for (int ch = 0; ch < 16; ++ch) {
        const int cb = cb0 + ch * 32;
        const unsigned short* wrow = wbase + (size_t)ch * 32 * 256;

        float wsqv[2];
        wsqv[0] = wsqs[ch * 32 + la];
        wsqv[1] = wsqs[ch * 32 + 16 + la];

        f32x4 acc[2];
        acc[0] = (f32x4){0.f, 0.f, 0.f, 0.f};
        acc[1] = (f32x4){0.f, 0.f, 0.f, 0.f};

        #pragma unroll
        for (int ks = 0; ks < 8; ++ks) {
            const bf16x8 b0 = *(const bf16x8*)(wrow + ks * 32);          // nf=0
            const bf16x8 b1 = *(const bf16x8*)(wrow + 4096 + ks * 32);   // nf=1
            acc[0] = __builtin_amdgcn_mfma_f32_16x16x32_bf16(af[ks], b0, acc[0], 0, 0, 0);
            acc[1] = __builtin_amdgcn_mfma_f32_16x16x32_bf16(af[ks], b1, acc[1], 0, 0, 0);
        }

        float da[2][4];
        #pragma unroll
        for (int nf = 0; nf < 2; ++nf)
            #pragma unroll
            for (int r = 0; r < 4; ++r)
                da[nf][r] = __builtin_fmaf(-2.f, acc[nf][r], wsqv[nf]);

        #pragma unroll
        for (int r = 0; r < 4; ++r) {
            float mv = fminf(da[0][r], da[1][r]);
            #pragma unroll
            for (int off = 1; off < 16; off <<= 1)
                mv = fminf(mv, __shfl_xor(mv, off));
            rg[r] = fminf(rg[r], mv);
        }

        #pragma unroll
        for (int nf = 0; nf < 2; ++nf)
            #pragma unroll
            for (int r = 0; r < 4; ++r)
                if (da[nf][r] <= rg[r] + EPS_SCREEN) {
                    const int p = m0 + kg * 4 + r;
                    const int slot = atomicAdd(&candCnt[p], 1);
                    if (slot < CAND_CAP) {
                        candC[(size_t)p * CAND_CAP + slot] =
                            (unsigned short)(cb + nf * 16 + la);
                        candD[(size_t)p * CAND_CAP + slot] = da[nf][r];
                    }
                }
    }
}

// ---------------------------------------------------------------------------
// k2r: viability-filtered exact rescore. UNCHANGED from validated R12-R17.
// ---------------------------------------------------------------------------
__launch_bounds__(256, 4)
__global__ void k2r_rescore(const float* __restrict__ z, const float* __restrict__ wemb,
                            const float* __restrict__ wsq,
                            const unsigned short* __restrict__ candC,
                            const float* __restrict__ candD,
                            const int* __restrict__ candCnt,
                            float* __restrict__ idx_out) {
    __shared__ float t32[32 * 256];   // 32 KB
    const int tid = threadIdx.x;
    const int wv = tid >> 6, l = tid & 63;
    const int p0 = blockIdx.x * 32;
    const int n = p0 >> 10, hw0 = p0 & 1023;

    // ---- metadata prefetch (independent of staging) ----
    const int pl = tid >> 3, slot = tid & 7;
    const int p = p0 + pl;
    const int count = candCnt[p];
    const int c0raw = candC[(size_t)p * CAND_CAP + slot];
    const float da0 = candD[(size_t)p * CAND_CAP + slot];

    // ---- stage z tile [32 hw][256 k] fp32, coalesced, b128 LDS writes ----
    const int row = l & 31;
    const int xmr = (row & 7) * 4;
    #pragma unroll
    for (int i = 0; i < 8; ++i) {
        const int k4 = i * 32 + wv * 8 + (l >> 5) * 4;
        const size_t zb = ((size_t)(n * 256 + k4) << 10) + hw0 + row;
        float4 v;
        v.x = z[zb];
        v.y = z[zb + 1024];
        v.z = z[zb + 2048];
        v.w = z[zb + 3072];
        *(float4*)&t32[row * 256 + (k4 ^ xmr)] = v;
    }

    // ---- viability filter (registers + shuffles only) ----
    bool need;                // position requires exact dots
    float thr = 0.f;
    if (count <= CAND_CAP) {
        const int nr = (count + 7) >> 3;
        float m = (slot < count) ? da0 : FLT_MAX;
        for (int rr = 1; rr < nr; ++rr) {
            const int s = rr * 8 + slot;
            if (s < count) m = fminf(m, candD[(size_t)p * CAND_CAP + s]);
        }
        #pragma unroll
        for (int off = 1; off < 8; off <<= 1) m = fminf(m, __shfl_xor(m, off));
        thr = m + EPS_SCREEN;

        int V;
        int soleC = N_CODES;
        {
            const bool v0 = (slot < count) && (da0 <= thr);
            const unsigned long long mask = __ballot(v0);
            V = __popcll((mask >> ((l >> 3) * 8)) & 0xFFull);
            if (v0) soleC = c0raw;
        }
        for (int rr = 1; rr < nr; ++rr) {
            const int s = rr * 8 + slot;
            bool vs = false;
            if (s < count) {
                vs = (candD[(size_t)p * CAND_CAP + s] <= thr);
                if (vs && soleC == N_CODES) soleC = candC[(size_t)p * CAND_CAP + s];
            }
            const unsigned long long mask = __ballot(vs);
            V += __popcll((mask >> ((l >> 3) * 8)) & 0xFFull);
        }
        if (V == 1 && soleC != N_CODES) idx_out[p] = (float)soleC;
        need = (V >= 2);
    } else {
        need = true;   // overflow: full sweep below
    }

    __syncthreads();   // z tile ready

    if (!need) return;   // uniform across each 8-lane position group

    const float* zrow = &t32[pl * 256];
    const int xm = (pl & 7) * 4;

    // ---- zsq: numpy pairwise 128+128, 8 accumulators (exact k1 order) ----
    float halfv[2];
    #pragma unroll
    for (int h = 0; h < 2; ++h) {
        float r[8];
        {
            const f32x4 a = *(const f32x4*)&zrow[(h * 128) ^ xm];
            const f32x4 b = *(const f32x4*)&zrow[(h * 128 + 4) ^ xm];
            #pragma unroll
            for (int j = 0; j < 4; ++j) { r[j] = sq_sep(a[j]); r[4 + j] = sq_sep(b[j]); }
        }
        for (int i = 8; i < 128; i += 8) {
            const f32x4 a = *(const f32x4*)&zrow[(h * 128 + i) ^ xm];
            const f32x4 b = *(const f32x4*)&zrow[(h * 128 + i + 4) ^ xm];
            #pragma unroll
            for (int j = 0; j < 4; ++j) { r[j] += sq_sep(a[j]); r[4 + j] += sq_sep(b[j]); }
        }
        halfv[h] = ((r[0] + r[1]) + (r[2] + r[3])) + ((r[4] + r[5]) + (r[6] + r[7]));
    }
    const float zsv = halfv[0] + halfv[1];

#define DOT_CHAIN(wb_, dot_) do {                                              \
    _Pragma("unroll")                                                          \
    for (int kb = 0; kb < 256; kb += 8) {                                      \
        const f32x4 za = *(const f32x4*)&zrow[kb ^ xm];                        \
        const f32x4 zb4 = *(const f32x4*)&zrow[(kb + 4) ^ xm];                 \
        const float4 wa = *(const float4*)&(wb_)[kb];                          \
        const float4 wc = *(const float4*)&(wb_)[kb + 4];                      \
        dot_ = __builtin_fmaf(za[0], wa.x, dot_);                              \
        dot_ = __builtin_fmaf(za[1], wa.y, dot_);                              \
        dot_ = __builtin_fmaf(za[2], wa.z, dot_);                              \
        dot_ = __builtin_fmaf(za[3], wa.w, dot_);                              \
        dot_ = __builtin_fmaf(zb4[0], wc.x, dot_);                             \
        dot_ = __builtin_fmaf(zb4[1], wc.y, dot_);                             \
        dot_ = __builtin_fmaf(zb4[2], wc.z, dot_);                             \
        dot_ = __builtin_fmaf(zb4[3], wc.w, dot_);                             \
    }                                                                          \
} while (0)

    float bd = FLT_MAX;
    int bc = N_CODES;

    if (count <= CAND_CAP) {
        const int nr = (count + 7) >> 3;
        for (int rr = 0; rr < nr; ++rr) {
            const int s = rr * 8 + slot;
            int c; float das;
            if (rr == 0) { c = c0raw; das = da0; }
            else if (s < count) {
                c = candC[(size_t)p * CAND_CAP + s];
                das = candD[(size_t)p * CAND_CAP + s];
            } else { c = N_CODES; das = FLT_MAX; }
            if (s < count && das <= thr) {        // viable only
                const float* wb = wemb + (size_t)c * 256;
                float dot = 0.f;
                DOT_CHAIN(wb, dot);
                const float d = __builtin_fmaf(-2.f, dot, zsv) + wsq[c];
                if (d < bd || (d == bd && c < bc)) { bd = d; bc = c; }
            }
        }
    } else {
        for (int rr = 0; rr < 128; ++rr) {
            const int c = rr * 8 + slot;
            const float* wb = wemb + (size_t)c * 256;
            float dot = 0.f;
            DOT_CHAIN(wb, dot);
            const float d = __builtin_fmaf(-2.f, dot, zsv) + wsq[c];
            if (d < bd || (d == bd && c < bc)) { bd = d; bc = c; }
        }
    }
#undef DOT_CHAIN

    // lex-min (d, c) across the 8 slots of this position
    #pragma unroll
    for (int off = 1; off < 8; off <<= 1) {
        const float od = __shfl_xor(bd, off);
        const int   oi = __shfl_xor(bc, off);
        if (od < bd || (od == bd && oi < bc)) { bd = od; bc = oi; }
    }
    if (slot == 0) idx_out[p] = (float)bc;
}

// ---------------------------------------------------------------------------
// k3: gather + straight-through. Block = fixed (n, c); Wt column staged
// coalesced into LDS. UNCHANGED from validated R10.
// ---------------------------------------------------------------------------
__global__ void k3_gather(const float* __restrict__ z, const float* __restrict__ wtf,
                          const float* __restrict__ idxf,
                          float* __restrict__ out0, float* __restrict__ out1) {
    __shared__ float wcol[1024];
    const int tid = threadIdx.x;
    const int b = blockIdx.x;              // 8192 = 32 n x 256 c
    const int c = b & 255, n = b >> 8;
    *(float4*)&wcol[tid * 4] = *(const float4*)&wtf[(size_t)c * 1024 + tid * 4];
    __syncthreads();

    const size_t zo = (((size_t)(n * 256 + c)) << 10) + tid * 4;
    const float4 zv = *(const float4*)&z[zo];
    const float4 iv = *(const float4*)&idxf[n * 1024 + tid * 4];
    float4 qv, st;
    qv.x = wcol[(int)iv.x]; st.x = (qv.x - zv.x) + zv.x;
    qv.y = wcol[(int)iv.y]; st.y = (qv.y - zv.y) + zv.y;
    qv.z = wcol[(int)iv.z]; st.z = (qv.z - zv.z) + zv.z;
    qv.w = wcol[(int)iv.w]; st.w = (qv.w - zv.w) + zv.w;
    *(float4*)&out0[zo] = qv;
    *(float4*)&out1[zo] = st;
}

extern "C" void kernel_launch(void* const* d_in, const int* in_sizes, int n_in,
                              void* d_out, int out_size, void* d_ws, size_t ws_size,
                              hipStream_t stream) {
    const float* z = (const float*)d_in[0];
    const float* wemb = (const float*)d_in[1];
    float* out = (float*)d_out;
    float* out0 = out;                       // quantized (final)
    float* out1 = out + Q_ELEMS;             // straight_through (final)
    float* oidx = out + 2 * Q_ELEMS;         // indices-as-float (final)
    // big scratch inside d_out (all consumed before k3 overwrites):
    unsigned short* zhi = (unsigned short*)out0;                  // 16 MB  [0..4M floats)
    unsigned short* candC = (unsigned short*)(out0 + 4194304);    // 4 MB   [4M..5M floats)
    float* candD = out0 + 5242880;                                // 8 MB   [5M..7M floats)
    int* candCnt = (int*)(out0 + 7340032);                        // 128 KB [7M..7.03M)
    unsigned short* whi = (unsigned short*)out1;                  // 512 KB (out1 head)
    // d_ws scratch (~1.05 MB):
    float* wsq = (float*)d_ws;                // 1024 f32
    float* wtf = (float*)d_ws + 1024;         // 262144 f32 (Wt, exact f32)

    k0t_transpose<<<64, 256, 0, stream>>>(wemb, wtf);
    k0w_pack<<<128, 256, 0, stream>>>(wemb, whi);
    k0z_pack<<<512, 256, 0, stream>>>(z, zhi);
    k1_wsq<<<132, 256, 0, stream>>>(wemb, wsq, candCnt);
    k2s_screen<<<1024, 256, 0, stream>>>(zhi, whi, wsq, candC, candD, candCnt);
    k2r_rescore<<<P_TOTAL / 32, 256, 0, stream>>>(z, wemb, wsq, candC, candD, candCnt, oidx);
    k3_gather<<<8192, 256, 0, stream>>>(z, wtf, oidx, out0, out1);
}

// Round 19
// 217.905 us; speedup vs baseline: 1.0942x; 1.0942x over previous
//
#include <hip/hip_runtime.h>
#include <cfloat>

// Geometry: z (32,256,32,32) f32, W (1024,256) f32.
// P = 32768 (p = n*1024+hw), K = 256, CODES = 1024.
// d_out = [quantized 8388608][straight_through 8388608][indices-as-float 32768]
// Strategy: bf16 MFMA screen + viability filter + exact fp32 rescore.
// Screen v9: mi=2 (32 pos/wave, each B LDS read feeds 2 MFMAs), quarter
// blocks, grid 1024 = 4 blocks/CU, launch_bounds(256,3) -> VGPR cap 170
// (needs ~115: no forced spill — R13/R16 spilled at cap 128; R15 proved the
// allocator doesn't spill when the cap has headroom; R15's real failure was
// grid 512 = 2 blocks/CU).

#define P_TOTAL   32768
#define N_CODES   1024
#define Q_ELEMS   8388608
#define EPS_SCREEN 4.0e-3f   // rigorous bf16-screen bound B~1.1e-3; EPS > 2B
#define CAND_CAP  64

typedef __attribute__((ext_vector_type(8))) short bf16x8;
typedef __attribute__((ext_vector_type(4))) float f32x4;

#define GLOAD16(gsrc, ldst) \
  __builtin_amdgcn_global_load_lds((const __attribute__((address_space(1))) void*)(gsrc), \
                                   (__attribute__((address_space(3))) void*)(ldst), 16, 0, 0)

__device__ __forceinline__ unsigned short f2bf(float f) {   // RN-even f32->bf16
    unsigned u = __builtin_bit_cast(unsigned, f);
    u += 0x7FFF + ((u >> 16) & 1);
    return (unsigned short)(u >> 16);
}

__device__ __forceinline__ float sq_sep(float v) {
    float t = v * v;
    asm volatile("" : "+v"(t));
    return t;
}

// ---------------------------------------------------------------------------
// k0t: W[1024][256] -> Wtf[256][1024] f32 (exact copy; validated R2/R10).
// ---------------------------------------------------------------------------
__global__ void k0t_transpose(const float* __restrict__ wemb, float* __restrict__ wt) {
    __shared__ float tile[64 * 65];
    const int tid = threadIdx.x;
    const int ct = blockIdx.x >> 2, kt = blockIdx.x & 3;
    const int c0 = ct * 64, k0 = kt * 64;
    const int rr = tid >> 4, cg = tid & 15;
    #pragma unroll
    for (int i = 0; i < 4; ++i) {
        const int row = i * 16 + rr;
        const float4 v = *(const float4*)&wemb[(size_t)(c0 + row) * 256 + k0 + cg * 4];
        tile[row * 65 + cg * 4 + 0] = v.x;
        tile[row * 65 + cg * 4 + 1] = v.y;
        tile[row * 65 + cg * 4 + 2] = v.z;
        tile[row * 65 + cg * 4 + 3] = v.w;
    }
    __syncthreads();
    #pragma unroll
    for (int i = 0; i < 4; ++i) {
        const int krow = i * 16 + rr;
        float4 v;
        v.x = tile[(cg * 4 + 0) * 65 + krow];
        v.y = tile[(cg * 4 + 1) * 65 + krow];
        v.z = tile[(cg * 4 + 2) * 65 + krow];
        v.w = tile[(cg * 4 + 3) * 65 + krow];
        *(float4*)&wt[(size_t)(k0 + krow) * 1024 + c0 + cg * 4] = v;
    }
}

// ---------------------------------------------------------------------------
// k0w: W -> W_hi bf16; 16B granules XOR-swizzled (slot g^(c&7) per 512B row)
// — matches k2s v9's un-swizzled LDS fragment reads (validated R12/R13).
// ---------------------------------------------------------------------------
__global__ void k0w_pack(const float* __restrict__ wemb, unsigned short* __restrict__ whi) {
    const int t = blockIdx.x * 256 + threadIdx.x;   // 32768 granules
    const int c = t >> 5, g = t & 31;
    const float4 v0 = *(const float4*)&wemb[(size_t)c * 256 + g * 8];
    const float4 v1 = *(const float4*)&wemb[(size_t)c * 256 + g * 8 + 4];
    bf16x8 hv;
    hv[0] = (short)f2bf(v0.x); hv[1] = (short)f2bf(v0.y);
    hv[2] = (short)f2bf(v0.z); hv[3] = (short)f2bf(v0.w);
    hv[4] = (short)f2bf(v1.x); hv[5] = (short)f2bf(v1.y);
    hv[6] = (short)f2bf(v1.z); hv[7] = (short)f2bf(v1.w);
    const int gs = g ^ (c & 7);
    *(bf16x8*)(whi + (size_t)c * 256 + gs * 8) = hv;
}

// ---------------------------------------------------------------------------
// k0z: z [n][k][hw] f32 -> z_hi [p][k] bf16 (transpose via LDS). grid 512.
// ---------------------------------------------------------------------------
#define T16S 280   // ushort stride: 560B rows (16B aligned)
__global__ void k0z_pack(const float* __restrict__ z, unsigned short* __restrict__ zhi) {
    __shared__ unsigned short t16[64 * T16S];   // 35,840 B
    const int tid = threadIdx.x;
    const int n = blockIdx.x >> 4, hc = blockIdx.x & 15;
    const int hw0 = hc * 64;
    const int w = tid >> 6, hl = tid & 63;
    #pragma unroll
    for (int i = 0; i < 64; ++i) {
        const int k = i * 4 + w;
        const float v = z[((size_t)(n * 256 + k) << 10) + hw0 + hl];
        t16[hl * T16S + k] = f2bf(v);
    }
    __syncthreads();
    const int row = tid >> 2, cp = tid & 3;
    const size_t p0 = (size_t)(n * 1024 + hw0);
    #pragma unroll
    for (int i = 0; i < 8; ++i) {
        const int chunk = i * 4 + cp;
        *(bf16x8*)(zhi + (p0 + row) * 256 + chunk * 8) =
            *(const bf16x8*)&t16[row * T16S + chunk * 8];
    }
}

// ---------------------------------------------------------------------------
// k1: blocks 0-3: wsq[c] (numpy pairwise order). blocks 4-131: zero candCnt.
// ---------------------------------------------------------------------------
__global__ void k1_wsq(const float* __restrict__ wemb, float* __restrict__ wsq,
                       int* __restrict__ candCnt) {
    const int b = blockIdx.x, tid = threadIdx.x;
    if (b >= 4) { candCnt[(b - 4) * 256 + tid] = 0; return; }
    const int c = b * 256 + tid;
    const float* base = wemb + (size_t)c * 256;
    float half[2];
    #pragma unroll
    for (int h = 0; h < 2; ++h) {
        const float* x = base + h * 128;
        float r[8];
        #pragma unroll
        for (int j = 0; j < 8; ++j) r[j] = sq_sep(x[j]);
        for (int i = 8; i < 128; i += 8) {
            #pragma unroll
            for (int j = 0; j < 8; ++j) r[j] += sq_sep(x[i + j]);
        }
        half[h] = ((r[0] + r[1]) + (r[2] + r[3])) + ((r[4] + r[5]) + (r[6] + r[7]));
    }
    wsq[c] = half[0] + half[1];
}

// ---------------------------------------------------------------------------
// k2s v9: bf16 MFMA screen, mi=2 (32 pos/wave). Block = 128 pos x 256 codes
// (quarter q), 8 chunks of 32; grid 1024 = 256 pgrp x 4 q = 4 blocks/CU.
// launch_bounds(256,3): VGPR cap 170, need ~115 -> no spill; LDS 33KB x4 =
// 132KB -> 4 blocks/CU resident (16 waves, ~50% occ). XCD bid map keeps a
// pgrp's quarters on one XCD (zhi L2 reuse). Each bf LDS read feeds 2 MFMAs.
// Collect semantics = validated R13 quarter-superset + R14 collect-skip.
// ---------------------------------------------------------------------------
__launch_bounds__(256, 3)
__global__ void k2s_screen(const unsigned short* __restrict__ zhi,
                           const unsigned short* __restrict__ whi,
                           const float* __restrict__ wsq,
                           unsigned short* __restrict__ candC,
                           float* __restrict__ candD,
                           int* __restrict__ candCnt) {
    __shared__ unsigned short Bs[2][32 * 256];   // 16 KB x2
    __shared__ float wsqs[256];                  // this quarter's norms
    const int tid = threadIdx.x, bid = blockIdx.x;
    const int pgrp = (bid & 7) | ((bid >> 5) << 3);   // 0..255
    const int q = (bid >> 3) & 3;
    const int w = tid >> 6, l = tid & 63;
    const int la = l & 15, kg = l >> 4;
    const int m0 = pgrp * 128 + w * 32;
    const int cb0 = q * 256;

    wsqs[tid] = wsq[cb0 + tid];

    bf16x8 af[2][8];
    #pragma unroll
    for (int mi = 0; mi < 2; ++mi)
        #pragma unroll
        for (int ks = 0; ks < 8; ++ks)
            af[mi][ks] = *(const bf16x8*)(zhi + (size_t)(m0 + mi * 16 + la) * 256
                                          + ks * 32 + kg * 8);

    float rg[2][4];
    #pragma unroll
    for (int mi = 0; mi < 2; ++mi)
        #pragma unroll
        for (int r = 0; r < 4; ++r) rg[mi][r] = FLT_MAX;

#define STAGEB(buf, cb_) do {                                                  \
    const unsigned short* src_ = whi + (size_t)(cb_) * 256;                    \
    _Pragma("unroll")                                                          \
    for (int i_ = 0; i_ < 4; ++i_)                                             \
        GLOAD16(src_ + i_ * 2048 + tid * 8, &Bs[buf][i_ * 2048 + tid * 8]);    \
} while (0)

    STAGEB(0, cb0);
    __syncthreads();                      // wsqs ready + Bs[0] landed

    for (int ch = 0; ch < 8; ++ch) {
        const int cur = ch & 1;
        const int cb = cb0 + ch * 32;
        if (ch < 7) STAGEB(cur ^ 1, cb + 32);

        float wsqv[2];
        #pragma unroll
        for (int nf = 0; nf < 2; ++nf) wsqv[nf] = wsqs[ch * 32 + nf * 16 + la];

        f32x4 acc[2][2];
        #pragma unroll
        for (int mi = 0; mi < 2; ++mi)
            #pragma unroll
            for (int nf = 0; nf < 2; ++nf) acc[mi][nf] = (f32x4){0.f, 0.f, 0.f, 0.f};

        #pragma unroll
        for (int ks = 0; ks < 8; ++ks) {
            #pragma unroll
            for (int nf = 0; nf < 2; ++nf) {
                const int cl = nf * 16 + la;
                const int slot = (ks * 4 + kg) ^ (cl & 7);   // un-swizzle
                const bf16x8 bf = *(const bf16x8*)&Bs[cur][cl * 256 + slot * 8];
                acc[0][nf] = __builtin_amdgcn_mfma_f32_16x16x32_bf16(
                    af[0][ks], bf, acc[0][nf], 0, 0, 0);
                acc[1][nf] = __builtin_amdgcn_mfma_f32_16x16x32_bf16(
                    af[1][ks], bf, acc[1][nf], 0, 0, 0);
            }
        }

        float da[2][2][4];
        #pragma unroll
        for (int mi = 0; mi < 2; ++mi)
            #pragma unroll
            for (int nf = 0; nf < 2; ++nf)
                #pragma unroll
                for (int r = 0; r < 4; ++r)
                    da[mi][nf][r] = __builtin_fmaf(-2.f, acc[mi][nf][r], wsqv[nf]);

        bool need = false;
        #pragma unroll
        for (int mi = 0; mi < 2; ++mi)
            #pragma unroll
            for (int r = 0; r < 4; ++r) {
                float mv = fminf(da[mi][0][r], da[mi][1][r]);
                #pragma unroll
                for (int off = 1; off < 16; off <<= 1)
                    mv = fminf(mv, __shfl_xor(mv, off));
                need = need || (mv <= rg[mi][r] + EPS_SCREEN);   // vs rg_old
                rg[mi][r] = fminf(rg[mi][r], mv);
            }

        if (need) {   // uniform within each 16-lane group
            #pragma unroll
            for (int mi = 0; mi < 2; ++mi)
                #pragma unroll
                for (int nf = 0; nf < 2; ++nf)
                    #pragma unroll
                    for (int r = 0; r < 4; ++r)
                        if (da[mi][nf][r] <= rg[mi][r] + EPS_SCREEN) {
                            const int p = m0 + mi * 16 + kg * 4 + r;
                            const int slot = atomicAdd(&candCnt[p], 1);
                            if (slot < CAND_CAP) {
                                candC[(size_t)p * CAND_CAP + slot] =
                                    (unsigned short)(cb + nf * 16 + la);
                                candD[(size_t)p * CAND_CAP + slot] = da[mi][nf][r];
                            }
                        }
        }

        __syncthreads();   // Bs[cur] reads done; Bs[cur^1] landed (vmcnt(0))
    }
#undef STAGEB
}

// ---------------------------------------------------------------------------
// k2r: viability-filtered exact rescore. UNCHANGED from validated R12-R18.
// ---------------------------------------------------------------------------
__launch_bounds__(256, 4)
__global__ void k2r_rescore(const float* __restrict__ z, const float* __restrict__ wemb,
                            const float* __restrict__ wsq,
                            const unsigned short* __restrict__ candC,
                            const float* __restrict__ candD,
                            const int* __restrict__ candCnt,
                            float* __restrict__ idx_out) {
    __shared__ float t32[32 * 256];   // 32 KB
    const int tid = threadIdx.x;
    const int wv = tid >> 6, l = tid & 63;
    const int p0 = blockIdx.x * 32;
    const int n = p0 >> 10, hw0 = p0 & 1023;

    // ---- metadata prefetch (independent of staging) ----
    const int pl = tid >> 3, slot = tid & 7;
    const int p = p0 + pl;
    const int count = candCnt[p];
    const int c0raw = candC[(size_t)p * CAND_CAP + slot];
    const float da0 = candD[(size_t)p * CAND_CAP + slot];

    // ---- stage z tile [32 hw][256 k] fp32, coalesced, b128 LDS writes ----
    const int row = l & 31;
    const int xmr = (row & 7) * 4;
    #pragma unroll
    for (int i = 0; i < 8; ++i) {
        const int k4 = i * 32 + wv * 8 + (l >> 5) * 4;
        const size_t zb = ((size_t)(n * 256 + k4) << 10) + hw0 + row;
        float4 v;
        v.x = z[zb];
        v.y = z[zb + 1024];
        v.z = z[zb + 2048];
        v.w = z[zb + 3072];
        *(float4*)&t32[row * 256 + (k4 ^ xmr)] = v;
    }

    // ---- viability filter (registers + shuffles only) ----
    bool need;                // position requires exact dots
    float thr = 0.f;
    if (count <= CAND_CAP) {
        const int nr = (count + 7) >> 3;
        float m = (slot < count) ? da0 : FLT_MAX;
        for (int rr = 1; rr < nr; ++rr) {
            const int s = rr * 8 + slot;
            if (s < count) m = fminf(m, candD[(size_t)p * CAND_CAP + s]);
        }
        #pragma unroll
        for (int off = 1; off < 8; off <<= 1) m = fminf(m, __shfl_xor(m, off));
        thr = m + EPS_SCREEN;

        int V;
        int soleC = N_CODES;
        {
            const bool v0 = (slot < count) && (da0 <= thr);
            const unsigned long long mask = __ballot(v0);
            V = __popcll((mask >> ((l >> 3) * 8)) & 0xFFull);
            if (v0) soleC = c0raw;
        }
        for (int rr = 1; rr < nr; ++rr) {
            const int s = rr * 8 + slot;
            bool vs = false;
            if (s < count) {
                vs = (candD[(size_t)p * CAND_CAP + s] <= thr);
                if (vs && soleC == N_CODES) soleC = candC[(size_t)p * CAND_CAP + s];
            }
            const unsigned long long mask = __ballot(vs);
            V += __popcll((mask >> ((l >> 3) * 8)) & 0xFFull);
        }
        if (V == 1 && soleC != N_CODES) idx_out[p] = (float)soleC;
        need = (V >= 2);
    } else {
        need = true;   // overflow: full sweep below
    }

    __syncthreads();   // z tile ready

    if (!need) return;   // uniform across each 8-lane position group

    const float* zrow = &t32[pl * 256];
    const int xm = (pl & 7) * 4;

    // ---- zsq: numpy pairwise 128+128, 8 accumulators (exact k1 order) ----
    float halfv[2];
    #pragma unroll
    for (int h = 0; h < 2; ++h) {
        float r[8];
        {
            const f32x4 a = *(const f32x4*)&zrow[(h * 128) ^ xm];
            const f32x4 b = *(const f32x4*)&zrow[(h * 128 + 4) ^ xm];
            #pragma unroll
            for (int j = 0; j < 4; ++j) { r[j] = sq_sep(a[j]); r[4 + j] = sq_sep(b[j]); }
        }
        for (int i = 8; i < 128; i += 8) {
            const f32x4 a = *(const f32x4*)&zrow[(h * 128 + i) ^ xm];
            const f32x4 b = *(const f32x4*)&zrow[(h * 128 + i + 4) ^ xm];
            #pragma unroll
            for (int j = 0; j < 4; ++j) { r[j] += sq_sep(a[j]); r[4 + j] += sq_sep(b[j]); }
        }
        halfv[h] = ((r[0] + r[1]) + (r[2] + r[3])) + ((r[4] + r[5]) + (r[6] + r[7]));
    }
    const float zsv = halfv[0] + halfv[1];

#define DOT_CHAIN(wb_, dot_) do {                                              \
    _Pragma("unroll")                                                          \
    for (int kb = 0; kb < 256; kb += 8) {                                      \
        const f32x4 za = *(const f32x4*)&zrow[kb ^ xm];                        \
        const f32x4 zb4 = *(const f32x4*)&zrow[(kb + 4) ^ xm];                 \
        const float4 wa = *(const float4*)&(wb_)[kb];                          \
        const float4 wc = *(const float4*)&(wb_)[kb + 4];                      \
        dot_ = __builtin_fmaf(za[0], wa.x, dot_);                              \
        dot_ = __builtin_fmaf(za[1], wa.y, dot_);                              \
        dot_ = __builtin_fmaf(za[2], wa.z, dot_);                              \
        dot_ = __builtin_fmaf(za[3], wa.w, dot_);                              \
        dot_ = __builtin_fmaf(zb4[0], wc.x, dot_);                             \
        dot_ = __builtin_fmaf(zb4[1], wc.y, dot_);                             \
        dot_ = __builtin_fmaf(zb4[2], wc.z, dot_);                             \
        dot_ = __builtin_fmaf(zb4[3], wc.w, dot_);                             \
    }                                                                          \
} while (0)

    float bd = FLT_MAX;
    int bc = N_CODES;

    if (count <= CAND_CAP) {
        const int nr = (count + 7) >> 3;
        for (int rr = 0; rr < nr; ++rr) {
            const int s = rr * 8 + slot;
            int c; float das;
            if (rr == 0) { c = c0raw; das = da0; }
            else if (s < count) {
                c = candC[(size_t)p * CAND_CAP + s];
                das = candD[(size_t)p * CAND_CAP + s];
            } else { c = N_CODES; das = FLT_MAX; }
            if (s < count && das <= thr) {        // viable only
                const float* wb = wemb + (size_t)c * 256;
                float dot = 0.f;
                DOT_CHAIN(wb, dot);
                const float d = __builtin_fmaf(-2.f, dot, zsv) + wsq[c];
                if (d < bd || (d == bd && c < bc)) { bd = d; bc = c; }
            }
        }
    } else {
        for (int rr = 0; rr < 128; ++rr) {
            const int c = rr * 8 + slot;
            const float* wb = wemb + (size_t)c * 256;
            float dot = 0.f;
            DOT_CHAIN(wb, dot);
            const float d = __builtin_fmaf(-2.f, dot, zsv) + wsq[c];
            if (d < bd || (d == bd && c < bc)) { bd = d; bc = c; }
        }
    }
#undef DOT_CHAIN

    // lex-min (d, c) across the 8 slots of this position
    #pragma unroll
    for (int off = 1; off < 8; off <<= 1) {
        const float od = __shfl_xor(bd, off);
        const int   oi = __shfl_xor(bc, off);
        if (od < bd || (od == bd && oi < bc)) { bd = od; bc = oi; }
    }
    if (slot == 0) idx_out[p] = (float)bc;
}

// ---------------------------------------------------------------------------
// k3: gather + straight-through. Block = fixed (n, c); Wt column staged
// coalesced into LDS. UNCHANGED from validated R10.
// ---------------------------------------------------------------------------
__global__ void k3_gather(const float* __restrict__ z, const float* __restrict__ wtf,
                          const float* __restrict__ idxf,
                          float* __restrict__ out0, float* __restrict__ out1) {
    __shared__ float wcol[1024];
    const int tid = threadIdx.x;
    const int b = blockIdx.x;              // 8192 = 32 n x 256 c
    const int c = b & 255, n = b >> 8;
    *(float4*)&wcol[tid * 4] = *(const float4*)&wtf[(size_t)c * 1024 + tid * 4];
    __syncthreads();

    const size_t zo = (((size_t)(n * 256 + c)) << 10) + tid * 4;
    const float4 zv = *(const float4*)&z[zo];
    const float4 iv = *(const float4*)&idxf[n * 1024 + tid * 4];
    float4 qv, st;
    qv.x = wcol[(int)iv.x]; st.x = (qv.x - zv.x) + zv.x;
    qv.y = wcol[(int)iv.y]; st.y = (qv.y - zv.y) + zv.y;
    qv.z = wcol[(int)iv.z]; st.z = (qv.z - zv.z) + zv.z;
    qv.w = wcol[(int)iv.w]; st.w = (qv.w - zv.w) + zv.w;
    *(float4*)&out0[zo] = qv;
    *(float4*)&out1[zo] = st;
}

extern "C" void kernel_launch(void* const* d_in, const int* in_sizes, int n_in,
                              void* d_out, int out_size, void* d_ws, size_t ws_size,
                              hipStream_t stream) {
    const float* z = (const float*)d_in[0];
    const float* wemb = (const float*)d_in[1];
    float* out = (float*)d_out;
    float* out0 = out;                       // quantized (final)
    float* out1 = out + Q_ELEMS;             // straight_through (final)
    float* oidx = out + 2 * Q_ELEMS;         // indices-as-float (final)
    // big scratch inside d_out (all consumed before k3 overwrites):
    unsigned short* zhi = (unsigned short*)out0;                  // 16 MB  [0..4M floats)
    unsigned short* candC = (unsigned short*)(out0 + 4194304);    // 4 MB   [4M..5M floats)
    float* candD = out0 + 5242880;                                // 8 MB   [5M..7M floats)
    int* candCnt = (int*)(out0 + 7340032);                        // 128 KB [7M..7.03M)
    unsigned short* whi = (unsigned short*)out1;                  // 512 KB (out1 head)
    // d_ws scratch (~1.05 MB):
    float* wsq = (float*)d_ws;                // 1024 f32
    float* wtf = (float*)d_ws + 1024;         // 262144 f32 (Wt, exact f32)

    k0t_transpose<<<64, 256, 0, stream>>>(wemb, wtf);
    k0w_pack<<<128, 256, 0, stream>>>(wemb, whi);
    k0z_pack<<<512, 256, 0, stream>>>(z, zhi);
    k1_wsq<<<132, 256, 0, stream>>>(wemb, wsq, candCnt);
    k2s_screen<<<1024, 256, 0, stream>>>(zhi, whi, wsq, candC, candD, candCnt);
    k2r_rescore<<<P_TOTAL / 32, 256, 0, stream>>>(z, wemb, wsq, candC, candD, candCnt, oidx);
    k3_gather<<<8192, 256, 0, stream>>>(z, wtf, oidx, out0, out1);
}

// Round 20
// 165.508 us; speedup vs baseline: 1.4406x; 1.3166x over previous
//
#include <hip/hip_runtime.h>
#include <cfloat>

// Geometry: z (32,256,32,32) f32, W (1024,256) f32.
// P = 32768 (p = n*1024+hw), K = 256, CODES = 1024.
// d_out = [quantized 8388608][straight_through 8388608][indices-as-float 32768]
// Strategy: bf16 MFMA screen + viability filter + exact fp32 rescore.
// Screen v10 = R12's validated structure (16 pos/wave, half-split, grid 1024)
// with Bs in chunk-local [granule][code] layout: whi pre-permuted in GLOBAL,
// global_load_lds stays linear, fragment reads are 256B-contiguous per
// 16-lane group -> bank-conflict-free (R12 measured 16 extra cyc/read from
// the 3-bit-XOR layout: lanes la and la+8 shared a bank group).

#define P_TOTAL   32768
#define N_CODES   1024
#define Q_ELEMS   8388608
#define EPS_SCREEN 4.0e-3f   // rigorous bf16-screen bound B~1.1e-3; EPS > 2B
#define CAND_CAP  64

typedef __attribute__((ext_vector_type(8))) short bf16x8;
typedef __attribute__((ext_vector_type(4))) float f32x4;

#define GLOAD16(gsrc, ldst) \
  __builtin_amdgcn_global_load_lds((const __attribute__((address_space(1))) void*)(gsrc), \
                                   (__attribute__((address_space(3))) void*)(ldst), 16, 0, 0)

__device__ __forceinline__ unsigned short f2bf(float f) {   // RN-even f32->bf16
    unsigned u = __builtin_bit_cast(unsigned, f);
    u += 0x7FFF + ((u >> 16) & 1);
    return (unsigned short)(u >> 16);
}

__device__ __forceinline__ float sq_sep(float v) {
    float t = v * v;
    asm volatile("" : "+v"(t));
    return t;
}

// ---------------------------------------------------------------------------
// k0t: W[1024][256] -> Wtf[256][1024] f32 (exact copy; validated R2/R10).
// ---------------------------------------------------------------------------
__global__ void k0t_transpose(const float* __restrict__ wemb, float* __restrict__ wt) {
    __shared__ float tile[64 * 65];
    const int tid = threadIdx.x;
    const int ct = blockIdx.x >> 2, kt = blockIdx.x & 3;
    const int c0 = ct * 64, k0 = kt * 64;
    const int rr = tid >> 4, cg = tid & 15;
    #pragma unroll
    for (int i = 0; i < 4; ++i) {
        const int row = i * 16 + rr;
        const float4 v = *(const float4*)&wemb[(size_t)(c0 + row) * 256 + k0 + cg * 4];
        tile[row * 65 + cg * 4 + 0] = v.x;
        tile[row * 65 + cg * 4 + 1] = v.y;
        tile[row * 65 + cg * 4 + 2] = v.z;
        tile[row * 65 + cg * 4 + 3] = v.w;
    }
    __syncthreads();
    #pragma unroll
    for (int i = 0; i < 4; ++i) {
        const int krow = i * 16 + rr;
        float4 v;
        v.x = tile[(cg * 4 + 0) * 65 + krow];
        v.y = tile[(cg * 4 + 1) * 65 + krow];
        v.z = tile[(cg * 4 + 2) * 65 + krow];
        v.w = tile[(cg * 4 + 3) * 65 + krow];
        *(float4*)&wt[(size_t)(k0 + krow) * 1024 + c0 + cg * 4] = v;
    }
}

// ---------------------------------------------------------------------------
// k0w v2: W -> W_hi bf16 in chunk-local [granule][code] order:
// granule g (16B = 8 bf16, k = g*8..g*8+7) of code c lands at granule index
// (c>>5)*1024 + g*32 + (c&31). Staged linearly into LDS by k2s, this yields
// Bs[g][cl] and conflict-free 256B-contiguous fragment reads.
// ---------------------------------------------------------------------------
__global__ void k0w_pack(const float* __restrict__ wemb, unsigned short* __restrict__ whi) {
    const int t = blockIdx.x * 256 + threadIdx.x;   // 32768 granules
    const int c = t >> 5, g = t & 31;
    const float4 v0 = *(const float4*)&wemb[(size_t)c * 256 + g * 8];
    const float4 v1 = *(const float4*)&wemb[(size_t)c * 256 + g * 8 + 4];
    bf16x8 hv;
    hv[0] = (short)f2bf(v0.x); hv[1] = (short)f2bf(v0.y);
    hv[2] = (short)f2bf(v0.z); hv[3] = (short)f2bf(v0.w);
    hv[4] = (short)f2bf(v1.x); hv[5] = (short)f2bf(v1.y);
    hv[6] = (short)f2bf(v1.z); hv[7] = (short)f2bf(v1.w);
    const size_t og = (size_t)(c >> 5) * 1024 + g * 32 + (c & 31);
    *(bf16x8*)(whi + og * 8) = hv;
}

// ---------------------------------------------------------------------------
// k0z: z [n][k][hw] f32 -> z_hi [p][k] bf16 (transpose via LDS). grid 512.
// ---------------------------------------------------------------------------
#define T16S 280   // ushort stride: 560B rows (16B aligned)
__global__ void k0z_pack(const float* __restrict__ z, unsigned short* __restrict__ zhi) {
    __shared__ unsigned short t16[64 * T16S];   // 35,840 B
    const int tid = threadIdx.x;
    const int n = blockIdx.x >> 4, hc = blockIdx.x & 15;
    const int hw0 = hc * 64;
    const int w = tid >> 6, hl = tid & 63;
    #pragma unroll
    for (int i = 0; i < 64; ++i) {
        const int k = i * 4 + w;
        const float v = z[((size_t)(n * 256 + k) << 10) + hw0 + hl];
        t16[hl * T16S + k] = f2bf(v);
    }
    __syncthreads();
    const int row = tid >> 2, cp = tid & 3;
    const size_t p0 = (size_t)(n * 1024 + hw0);
    #pragma unroll
    for (int i = 0; i < 8; ++i) {
        const int chunk = i * 4 + cp;
        *(bf16x8*)(zhi + (p0 + row) * 256 + chunk * 8) =
            *(const bf16x8*)&t16[row * T16S + chunk * 8];
    }
}

// ---------------------------------------------------------------------------
// k1: blocks 0-3: wsq[c] (numpy pairwise order). blocks 4-131: zero candCnt.
// ---------------------------------------------------------------------------
__global__ void k1_wsq(const float* __restrict__ wemb, float* __restrict__ wsq,
                       int* __restrict__ candCnt) {
    const int b = blockIdx.x, tid = threadIdx.x;
    if (b >= 4) { candCnt[(b - 4) * 256 + tid] = 0; return; }
    const int c = b * 256 + tid;
    const float* base = wemb + (size_t)c * 256;
    float half[2];
    #pragma unroll
    for (int h = 0; h < 2; ++h) {
        const float* x = base + h * 128;
        float r[8];
        #pragma unroll
        for (int j = 0; j < 8; ++j) r[j] = sq_sep(x[j]);
        for (int i = 8; i < 128; i += 8) {
            #pragma unroll
            for (int j = 0; j < 8; ++j) r[j] += sq_sep(x[i + j]);
        }
        half[h] = ((r[0] + r[1]) + (r[2] + r[3])) + ((r[4] + r[5]) + (r[6] + r[7]));
    }
    wsq[c] = half[0] + half[1];
}

// ---------------------------------------------------------------------------
// k2s v10: bf16 MFMA screen = R12's validated structure + [g][cl] Bs layout.
// Block = 64 pos x 512 codes (half), 16 chunks of 32 codes; grid 1024.
// STAGEB linear (whi pre-permuted); fragment read at granule
// (ks*4+kg)*32 + nf*16 + la: 256B contiguous per 16-lane group -> no bank
// conflicts. Values bit-identical to R12 (same bf16 data, same MFMA order).
// ---------------------------------------------------------------------------
__launch_bounds__(256, 4)
__global__ void k2s_screen(const unsigned short* __restrict__ zhi,
                           const unsigned short* __restrict__ whi,
                           const float* __restrict__ wsq,
                           unsigned short* __restrict__ candC,
                           float* __restrict__ candD,
                           int* __restrict__ candCnt) {
    __shared__ unsigned short Bs[2][32 * 256];   // 16 KB x2
    const int tid = threadIdx.x, bid = blockIdx.x;
    const int pgrp = bid >> 1, half = bid & 1;
    const int w = tid >> 6, l = tid & 63;
    const int la = l & 15, kg = l >> 4;
    const int m0 = pgrp * 64 + w * 16;
    const int cb0 = half * 512;

    bf16x8 af[8];
    #pragma unroll
    for (int ks = 0; ks < 8; ++ks)
        af[ks] = *(const bf16x8*)(zhi + (size_t)(m0 + la) * 256 + ks * 32 + kg * 8);

    float rg[4];
    #pragma unroll
    for (int r = 0; r < 4; ++r) rg[r] = FLT_MAX;

// gch_ = global 32-code chunk index (0..31); whi stores 1024 granules/chunk
#define STAGEB(buf, gch_) do {                                                 \
    const unsigned short* src_ = whi + (size_t)(gch_) * 8192;                  \
    _Pragma("unroll")                                                          \
    for (int i_ = 0; i_ < 4; ++i_)                                             \
        GLOAD16(src_ + (i_ * 256 + tid) * 8, &Bs[buf][(i_ * 256 + tid) * 8]);  \
} while (0)

    STAGEB(0, half * 16);
    __syncthreads();                      // Bs[0] landed

    for (int ch = 0; ch < 16; ++ch) {
        const int cur = ch & 1;
        const int cb = cb0 + ch * 32;
        if (ch < 15) STAGEB(cur ^ 1, half * 16 + ch + 1);

        float wsqv[2];
        #pragma unroll
        for (int nf = 0; nf < 2; ++nf) wsqv[nf] = wsq[cb + nf * 16 + la];

        f32x4 acc[2];
        #pragma unroll
        for (int nf = 0; nf < 2; ++nf) acc[nf] = (f32x4){0.f, 0.f, 0.f, 0.f};

        #pragma unroll
        for (int ks = 0; ks < 8; ++ks) {
            bf16x8 bfv[2];
            #pragma unroll
            for (int nf = 0; nf < 2; ++nf) {
                const int gidx = (ks * 4 + kg) * 32 + nf * 16 + la;   // [g][cl]
                bfv[nf] = *(const bf16x8*)&Bs[cur][gidx * 8];
            }
            #pragma unroll
            for (int nf = 0; nf < 2; ++nf)
                acc[nf] = __builtin_amdgcn_mfma_f32_16x16x32_bf16(
                    af[ks], bfv[nf], acc[nf], 0, 0, 0);
        }

        float da[2][4];
        #pragma unroll
        for (int nf = 0; nf < 2; ++nf)
            #pragma unroll
            for (int r = 0; r < 4; ++r)
                da[nf][r] = __builtin_fmaf(-2.f, acc[nf][r], wsqv[nf]);

        #pragma unroll
        for (int r = 0; r < 4; ++r) {
            float mv = fminf(da[0][r], da[1][r]);
            #pragma unroll
            for (int off = 1; off < 16; off <<= 1)
                mv = fminf(mv, __shfl_xor(mv, off));
            rg[r] = fminf(rg[r], mv);
        }

        #pragma unroll
        for (int nf = 0; nf < 2; ++nf)
            #pragma unroll
            for (int r = 0; r < 4; ++r)
                if (da[nf][r] <= rg[r] + EPS_SCREEN) {
                    const int p = m0 + kg * 4 + r;
                    const int slot = atomicAdd(&candCnt[p], 1);
                    if (slot < CAND_CAP) {
                        candC[(size_t)p * CAND_CAP + slot] =
                            (unsigned short)(cb + nf * 16 + la);
                        candD[(size_t)p * CAND_CAP + slot] = da[nf][r];
                    }
                }

        __syncthreads();   // Bs[cur] reads done; Bs[cur^1] landed (vmcnt(0))
    }
#undef STAGEB
}

// ---------------------------------------------------------------------------
// k2r: viability-filtered exact rescore. UNCHANGED from validated R12-R19.
// ---------------------------------------------------------------------------
__launch_bounds__(256, 4)
__global__ void k2r_rescore(const float* __restrict__ z, const float* __restrict__ wemb,
                            const float* __restrict__ wsq,
                            const unsigned short* __restrict__ candC,
                            const float* __restrict__ candD,
                            const int* __restrict__ candCnt,
                            float* __restrict__ idx_out) {
    __shared__ float t32[32 * 256];   // 32 KB
    const int tid = threadIdx.x;
    const int wv = tid >> 6, l = tid & 63;
    const int p0 = blockIdx.x * 32;
    const int n = p0 >> 10, hw0 = p0 & 1023;

    // ---- metadata prefetch (independent of staging) ----
    const int pl = tid >> 3, slot = tid & 7;
    const int p = p0 + pl;
    const int count = candCnt[p];
    const int c0raw = candC[(size_t)p * CAND_CAP + slot];
    const float da0 = candD[(size_t)p * CAND_CAP + slot];

    // ---- stage z tile [32 hw][256 k] fp32, coalesced, b128 LDS writes ----
    const int row = l & 31;
    const int xmr = (row & 7) * 4;
    #pragma unroll
    for (int i = 0; i < 8; ++i) {
        const int k4 = i * 32 + wv * 8 + (l >> 5) * 4;
        const size_t zb = ((size_t)(n * 256 + k4) << 10) + hw0 + row;
        float4 v;
        v.x = z[zb];
        v.y = z[zb + 1024];
        v.z = z[zb + 2048];
        v.w = z[zb + 3072];
        *(float4*)&t32[row * 256 + (k4 ^ xmr)] = v;
    }

    // ---- viability filter (registers + shuffles only) ----
    bool need;                // position requires exact dots
    float thr = 0.f;
    if (count <= CAND_CAP) {
        const int nr = (count + 7) >> 3;
        float m = (slot < count) ? da0 : FLT_MAX;
        for (int rr = 1; rr < nr; ++rr) {
            const int s = rr * 8 + slot;
            if (s < count) m = fminf(m, candD[(size_t)p * CAND_CAP + s]);
        }
        #pragma unroll
        for (int off = 1; off < 8; off <<= 1) m = fminf(m, __shfl_xor(m, off));
        thr = m + EPS_SCREEN;

        int V;
        int soleC = N_CODES;
        {
            const bool v0 = (slot < count) && (da0 <= thr);
            const unsigned long long mask = __ballot(v0);
            V = __popcll((mask >> ((l >> 3) * 8)) & 0xFFull);
            if (v0) soleC = c0raw;
        }
        for (int rr = 1; rr < nr; ++rr) {
            const int s = rr * 8 + slot;
            bool vs = false;
            if (s < count) {
                vs = (candD[(size_t)p * CAND_CAP + s] <= thr);
                if (vs && soleC == N_CODES) soleC = candC[(size_t)p * CAND_CAP + s];
            }
            const unsigned long long mask = __ballot(vs);
            V += __popcll((mask >> ((l >> 3) * 8)) & 0xFFull);
        }
        if (V == 1 && soleC != N_CODES) idx_out[p] = (float)soleC;
        need = (V >= 2);
    } else {
        need = true;   // overflow: full sweep below
    }

    __syncthreads();   // z tile ready

    if (!need) return;   // uniform across each 8-lane position group

    const float* zrow = &t32[pl * 256];
    const int xm = (pl & 7) * 4;

    // ---- zsq: numpy pairwise 128+128, 8 accumulators (exact k1 order) ----
    float halfv[2];
    #pragma unroll
    for (int h = 0; h < 2; ++h) {
        float r[8];
        {
            const f32x4 a = *(const f32x4*)&zrow[(h * 128) ^ xm];
            const f32x4 b = *(const f32x4*)&zrow[(h * 128 + 4) ^ xm];
            #pragma unroll
            for (int j = 0; j < 4; ++j) { r[j] = sq_sep(a[j]); r[4 + j] = sq_sep(b[j]); }
        }
        for (int i = 8; i < 128; i += 8) {
            const f32x4 a = *(const f32x4*)&zrow[(h * 128 + i) ^ xm];
            const f32x4 b = *(const f32x4*)&zrow[(h * 128 + i + 4) ^ xm];
            #pragma unroll
            for (int j = 0; j < 4; ++j) { r[j] += sq_sep(a[j]); r[4 + j] += sq_sep(b[j]); }
        }
        halfv[h] = ((r[0] + r[1]) + (r[2] + r[3])) + ((r[4] + r[5]) + (r[6] + r[7]));
    }
    const float zsv = halfv[0] + halfv[1];

#define DOT_CHAIN(wb_, dot_) do {                                              \
    _Pragma("unroll")                                                          \
    for (int kb = 0; kb < 256; kb += 8) {                                      \
        const f32x4 za = *(const f32x4*)&zrow[kb ^ xm];                        \
        const f32x4 zb4 = *(const f32x4*)&zrow[(kb + 4) ^ xm];                 \
        const float4 wa = *(const float4*)&(wb_)[kb];                          \
        const float4 wc = *(const float4*)&(wb_)[kb + 4];                      \
        dot_ = __builtin_fmaf(za[0], wa.x, dot_);                              \
        dot_ = __builtin_fmaf(za[1], wa.y, dot_);                              \
        dot_ = __builtin_fmaf(za[2], wa.z, dot_);                              \
        dot_ = __builtin_fmaf(za[3], wa.w, dot_);                              \
        dot_ = __builtin_fmaf(zb4[0], wc.x, dot_);                             \
        dot_ = __builtin_fmaf(zb4[1], wc.y, dot_);                             \
        dot_ = __builtin_fmaf(zb4[2], wc.z, dot_);                             \
        dot_ = __builtin_fmaf(zb4[3], wc.w, dot_);                             \
    }                                                                          \
} while (0)

    float bd = FLT_MAX;
    int bc = N_CODES;

    if (count <= CAND_CAP) {
        const int nr = (count + 7) >> 3;
        for (int rr = 0; rr < nr; ++rr) {
            const int s = rr * 8 + slot;
            int c; float das;
            if (rr == 0) { c = c0raw; das = da0; }
            else if (s < count) {
                c = candC[(size_t)p * CAND_CAP + s];
                das = candD[(size_t)p * CAND_CAP + s];
            } else { c = N_CODES; das = FLT_MAX; }
            if (s < count && das <= thr) {        // viable only
                const float* wb = wemb + (size_t)c * 256;
                float dot = 0.f;
                DOT_CHAIN(wb, dot);
                const float d = __builtin_fmaf(-2.f, dot, zsv) + wsq[c];
                if (d < bd || (d == bd && c < bc)) { bd = d; bc = c; }
            }
        }
    } else {
        for (int rr = 0; rr < 128; ++rr) {
            const int c = rr * 8 + slot;
            const float* wb = wemb + (size_t)c * 256;
            float dot = 0.f;
            DOT_CHAIN(wb, dot);
            const float d = __builtin_fmaf(-2.f, dot, zsv) + wsq[c];
            if (d < bd || (d == bd && c < bc)) { bd = d; bc = c; }
        }
    }
#undef DOT_CHAIN

    // lex-min (d, c) across the 8 slots of this position
    #pragma unroll
    for (int off = 1; off < 8; off <<= 1) {
        const float od = __shfl_xor(bd, off);
        const int   oi = __shfl_xor(bc, off);
        if (od < bd || (od == bd && oi < bc)) { bd = od; bc = oi; }
    }
    if (slot == 0) idx_out[p] = (float)bc;
}

// ---------------------------------------------------------------------------
// k3: gather + straight-through. Block = fixed (n, c); Wt column staged
// coalesced into LDS. UNCHANGED from validated R10.
// ---------------------------------------------------------------------------
__global__ void k3_gather(const float* __restrict__ z, const float* __restrict__ wtf,
                          const float* __restrict__ idxf,
                          float* __restrict__ out0, float* __restrict__ out1) {
    __shared__ float wcol[1024];
    const int tid = threadIdx.x;
    const int b = blockIdx.x;              // 8192 = 32 n x 256 c
    const int c = b & 255, n = b >> 8;
    *(float4*)&wcol[tid * 4] = *(const float4*)&wtf[(size_t)c * 1024 + tid * 4];
    __syncthreads();

    const size_t zo = (((size_t)(n * 256 + c)) << 10) + tid * 4;
    const float4 zv = *(const float4*)&z[zo];
    const float4 iv = *(const float4*)&idxf[n * 1024 + tid * 4];
    float4 qv, st;
    qv.x = wcol[(int)iv.x]; st.x = (qv.x - zv.x) + zv.x;
    qv.y = wcol[(int)iv.y]; st.y = (qv.y - zv.y) + zv.y;
    qv.z = wcol[(int)iv.z]; st.z = (qv.z - zv.z) + zv.z;
    qv.w = wcol[(int)iv.w]; st.w = (qv.w - zv.w) + zv.w;
    *(float4*)&out0[zo] = qv;
    *(float4*)&out1[zo] = st;
}

extern "C" void kernel_launch(void* const* d_in, const int* in_sizes, int n_in,
                              void* d_out, int out_size, void* d_ws, size_t ws_size,
                              hipStream_t stream) {
    const float* z = (const float*)d_in[0];
    const float* wemb = (const float*)d_in[1];
    float* out = (float*)d_out;
    float* out0 = out;                       // quantized (final)
    float* out1 = out + Q_ELEMS;             // straight_through (final)
    float* oidx = out + 2 * Q_ELEMS;         // indices-as-float (final)
    // big scratch inside d_out (all consumed before k3 overwrites):
    unsigned short* zhi = (unsigned short*)out0;                  // 16 MB  [0..4M floats)
    unsigned short* candC = (unsigned short*)(out0 + 4194304);    // 4 MB   [4M..5M floats)
    float* candD = out0 + 5242880;                                // 8 MB   [5M..7M floats)
    int* candCnt = (int*)(out0 + 7340032);                        // 128 KB [7M..7.03M)
    unsigned short* whi = (unsigned short*)out1;                  // 512 KB (out1 head)
    // d_ws scratch (~1.05 MB):
    float* wsq = (float*)d_ws;                // 1024 f32
    float* wtf = (float*)d_ws + 1024;         // 262144 f32 (Wt, exact f32)

    k0t_transpose<<<64, 256, 0, stream>>>(wemb, wtf);
    k0w_pack<<<128, 256, 0, stream>>>(wemb, whi);
    k0z_pack<<<512, 256, 0, stream>>>(z, zhi);
    k1_wsq<<<132, 256, 0, stream>>>(wemb, wsq, candCnt);
    k2s_screen<<<1024, 256, 0, stream>>>(zhi, whi, wsq, candC, candD, candCnt);
    k2r_rescore<<<P_TOTAL / 32, 256, 0, stream>>>(z, wemb, wsq, candC, candD, candCnt, oidx);
    k3_gather<<<8192, 256, 0, stream>>>(z, wtf, oidx, out0, out1);
}

// Round 21
// 158.593 us; speedup vs baseline: 1.5034x; 1.0436x over previous
//
#include <hip/hip_runtime.h>
#include <cfloat>

// Geometry: z (32,256,32,32) f32, W (1024,256) f32.
// P = 32768 (p = n*1024+hw), K = 256, CODES = 1024.
// d_out = [quantized 8388608][straight_through 8388608][indices-as-float 32768]
// Strategy: bf16 MFMA screen + viability filter + exact fp32 rescore.
// R21 = R20 (best: 165.5us, all parts validated) with the four independent
// prelude kernels (k0t/k0w/k0z/k1) merged into ONE 836-block kernel:
// saves 3 launch gaps and fills the machine (each alone underfilled 256 CUs).
// All bodies token-identical to R20 -> outputs bit-identical.

#define P_TOTAL   32768
#define N_CODES   1024
#define Q_ELEMS   8388608
#define EPS_SCREEN 4.0e-3f   // rigorous bf16-screen bound B~1.1e-3; EPS > 2B
#define CAND_CAP  64

typedef __attribute__((ext_vector_type(8))) short bf16x8;
typedef __attribute__((ext_vector_type(4))) float f32x4;

#define GLOAD16(gsrc, ldst) \
  __builtin_amdgcn_global_load_lds((const __attribute__((address_space(1))) void*)(gsrc), \
                                   (__attribute__((address_space(3))) void*)(ldst), 16, 0, 0)

__device__ __forceinline__ unsigned short f2bf(float f) {   // RN-even f32->bf16
    unsigned u = __builtin_bit_cast(unsigned, f);
    u += 0x7FFF + ((u >> 16) & 1);
    return (unsigned short)(u >> 16);
}

__device__ __forceinline__ float sq_sep(float v) {
    float t = v * v;
    asm volatile("" : "+v"(t));
    return t;
}

// ---------------------------------------------------------------------------
// k0_prelude: merged k0t + k0w + k0z + k1 (mutually independent jobs).
//   blocks [0,64):    Wtf transpose (validated R2/R10)
//   blocks [64,192):  W_hi bf16 pack, chunk-local [granule][code] (R20)
//   blocks [192,704): z_hi bf16 pack via LDS transpose (R5-R20)
//   blocks [704,708): wsq (numpy pairwise order, R1-R20)
//   blocks [708,836): zero candCnt
// ---------------------------------------------------------------------------
#define T16S 280   // ushort stride: 560B rows (16B aligned)
__global__ void k0_prelude(const float* __restrict__ z, const float* __restrict__ wemb,
                           float* __restrict__ wt, unsigned short* __restrict__ whi,
                           unsigned short* __restrict__ zhi, float* __restrict__ wsq,
                           int* __restrict__ candCnt) {
    __shared__ union {
        float tile[64 * 65];               // 16,640 B (k0t)
        unsigned short t16[64 * T16S];     // 35,840 B (k0z)
    } u;
    const int b = blockIdx.x;
    const int tid = threadIdx.x;

    if (b < 64) {
        // ---- k0t: W[1024][256] -> Wtf[256][1024] f32 ----
        const int ct = b >> 2, kt = b & 3;
        const int c0 = ct * 64, k0 = kt * 64;
        const int rr = tid >> 4, cg = tid & 15;
        #pragma unroll
        for (int i = 0; i < 4; ++i) {
            const int row = i * 16 + rr;
            const float4 v = *(const float4*)&wemb[(size_t)(c0 + row) * 256 + k0 + cg * 4];
            u.tile[row * 65 + cg * 4 + 0] = v.x;
            u.tile[row * 65 + cg * 4 + 1] = v.y;
            u.tile[row * 65 + cg * 4 + 2] = v.z;
            u.tile[row * 65 + cg * 4 + 3] = v.w;
        }
        __syncthreads();
        #pragma unroll
        for (int i = 0; i < 4; ++i) {
            const int krow = i * 16 + rr;
            float4 v;
            v.x = u.tile[(cg * 4 + 0) * 65 + krow];
            v.y = u.tile[(cg * 4 + 1) * 65 + krow];
            v.z = u.tile[(cg * 4 + 2) * 65 + krow];
            v.w = u.tile[(cg * 4 + 3) * 65 + krow];
            *(float4*)&wt[(size_t)(k0 + krow) * 1024 + c0 + cg * 4] = v;
        }
    } else if (b < 192) {
        // ---- k0w: W -> W_hi bf16, chunk-local [granule][code] order ----
        const int t = (b - 64) * 256 + tid;   // 32768 granules
        const int c = t >> 5, g = t & 31;
        const float4 v0 = *(const float4*)&wemb[(size_t)c * 256 + g * 8];
        const float4 v1 = *(const float4*)&wemb[(size_t)c * 256 + g * 8 + 4];
        bf16x8 hv;
        hv[0] = (short)f2bf(v0.x); hv[1] = (short)f2bf(v0.y);
        hv[2] = (short)f2bf(v0.z); hv[3] = (short)f2bf(v0.w);
        hv[4] = (short)f2bf(v1.x); hv[5] = (short)f2bf(v1.y);
        hv[6] = (short)f2bf(v1.z); hv[7] = (short)f2bf(v1.w);
        const size_t og = (size_t)(c >> 5) * 1024 + g * 32 + (c & 31);
        *(bf16x8*)(whi + og * 8) = hv;
    } else if (b < 704) {
        // ---- k0z: z [n][k][hw] -> z_hi [p][k] bf16 (LDS transpose) ----
        const int bz = b - 192;
        const int n = bz >> 4, hc = bz & 15;
        const int hw0 = hc * 64;
        const int w = tid >> 6, hl = tid & 63;
        #pragma unroll
        for (int i = 0; i < 64; ++i) {
            const int k = i * 4 + w;
            const float v = z[((size_t)(n * 256 + k) << 10) + hw0 + hl];
            u.t16[hl * T16S + k] = f2bf(v);
        }
        __syncthreads();
        const int row = tid >> 2, cp = tid & 3;
        const size_t p0 = (size_t)(n * 1024 + hw0);
        #pragma unroll
        for (int i = 0; i < 8; ++i) {
            const int chunk = i * 4 + cp;
            *(bf16x8*)(zhi + (p0 + row) * 256 + chunk * 8) =
                *(const bf16x8*)&u.t16[row * T16S + chunk * 8];
        }
    } else if (b < 708) {
        // ---- k1: wsq[c], numpy pairwise 128+128, 8 accumulators ----
        const int c = (b - 704) * 256 + tid;
        const float* base = wemb + (size_t)c * 256;
        float half[2];
        #pragma unroll
        for (int h = 0; h < 2; ++h) {
            const float* x = base + h * 128;
            float r[8];
            #pragma unroll
            for (int j = 0; j < 8; ++j) r[j] = sq_sep(x[j]);
            for (int i = 8; i < 128; i += 8) {
                #pragma unroll
                for (int j = 0; j < 8; ++j) r[j] += sq_sep(x[i + j]);
            }
            half[h] = ((r[0] + r[1]) + (r[2] + r[3])) + ((r[4] + r[5]) + (r[6] + r[7]));
        }
        wsq[c] = half[0] + half[1];
    } else {
        // ---- zero candCnt ----
        candCnt[(b - 708) * 256 + tid] = 0;
    }
}

// ---------------------------------------------------------------------------
// k2s v10: bf16 MFMA screen (validated R20). Block = 64 pos x 512 codes
// (half), 16 chunks of 32 codes; grid 1024. Bs in chunk-local [g][cl] layout
// (whi pre-permuted; linear global_load_lds; conflict-free 256B reads).
// ---------------------------------------------------------------------------
__launch_bounds__(256, 4)
__global__ void k2s_screen(const unsigned short* __restrict__ zhi,
                           const unsigned short* __restrict__ whi,
                           const float* __restrict__ wsq,
                           unsigned short* __restrict__ candC,
                           float* __restrict__ candD,
                           int* __restrict__ candCnt) {
    __shared__ unsigned short Bs[2][32 * 256];   // 16 KB x2
    const int tid = threadIdx.x, bid = blockIdx.x;
    const int pgrp = bid >> 1, half = bid & 1;
    const int w = tid >> 6, l = tid & 63;
    const int la = l & 15, kg = l >> 4;
    const int m0 = pgrp * 64 + w * 16;
    const int cb0 = half * 512;

    bf16x8 af[8];
    #pragma unroll
    for (int ks = 0; ks < 8; ++ks)
        af[ks] = *(const bf16x8*)(zhi + (size_t)(m0 + la) * 256 + ks * 32 + kg * 8);

    float rg[4];
    #pragma unroll
    for (int r = 0; r < 4; ++r) rg[r] = FLT_MAX;

#define STAGEB(buf, gch_) do {                                                 \
    const unsigned short* src_ = whi + (size_t)(gch_) * 8192;                  \
    _Pragma("unroll")                                                          \
    for (int i_ = 0; i_ < 4; ++i_)                                             \
        GLOAD16(src_ + (i_ * 256 + tid) * 8, &Bs[buf][(i_ * 256 + tid) * 8]);  \
} while (0)

    STAGEB(0, half * 16);
    __syncthreads();                      // Bs[0] landed

    for (int ch = 0; ch < 16; ++ch) {
        const int cur = ch & 1;
        const int cb = cb0 + ch * 32;
        if (ch < 15) STAGEB(cur ^ 1, half * 16 + ch + 1);

        float wsqv[2];
        #pragma unroll
        for (int nf = 0; nf < 2; ++nf) wsqv[nf] = wsq[cb + nf * 16 + la];

        f32x4 acc[2];
        #pragma unroll
        for (int nf = 0; nf < 2; ++nf) acc[nf] = (f32x4){0.f, 0.f, 0.f, 0.f};

        #pragma unroll
        for (int ks = 0; ks < 8; ++ks) {
            bf16x8 bfv[2];
            #pragma unroll
            for (int nf = 0; nf < 2; ++nf) {
                const int gidx = (ks * 4 + kg) * 32 + nf * 16 + la;   // [g][cl]
                bfv[nf] = *(const bf16x8*)&Bs[cur][gidx * 8];
            }
            #pragma unroll
            for (int nf = 0; nf < 2; ++nf)
                acc[nf] = __builtin_amdgcn_mfma_f32_16x16x32_bf16(
                    af[ks], bfv[nf], acc[nf], 0, 0, 0);
        }

        float da[2][4];
        #pragma unroll
        for (int nf = 0; nf < 2; ++nf)
            #pragma unroll
            for (int r = 0; r < 4; ++r)
                da[nf][r] = __builtin_fmaf(-2.f, acc[nf][r], wsqv[nf]);

        #pragma unroll
        for (int r = 0; r < 4; ++r) {
            float mv = fminf(da[0][r], da[1][r]);
            #pragma unroll
            for (int off = 1; off < 16; off <<= 1)
                mv = fminf(mv, __shfl_xor(mv, off));
            rg[r] = fminf(rg[r], mv);
        }

        #pragma unroll
        for (int nf = 0; nf < 2; ++nf)
            #pragma unroll
            for (int r = 0; r < 4; ++r)
                if (da[nf][r] <= rg[r] + EPS_SCREEN) {
                    const int p = m0 + kg * 4 + r;
                    const int slot = atomicAdd(&candCnt[p], 1);
                    if (slot < CAND_CAP) {
                        candC[(size_t)p * CAND_CAP + slot] =
                            (unsigned short)(cb + nf * 16 + la);
                        candD[(size_t)p * CAND_CAP + slot] = da[nf][r];
                    }
                }

        __syncthreads();   // Bs[cur] reads done; Bs[cur^1] landed (vmcnt(0))
    }
#undef STAGEB
}

// ---------------------------------------------------------------------------
// k2r: viability-filtered exact rescore. UNCHANGED from validated R12-R20.
// ---------------------------------------------------------------------------
__launch_bounds__(256, 4)
__global__ void k2r_rescore(const float* __restrict__ z, const float* __restrict__ wemb,
                            const float* __restrict__ wsq,
                            const unsigned short* __restrict__ candC,
                            const float* __restrict__ candD,
                            const int* __restrict__ candCnt,
                            float* __restrict__ idx_out) {
    __shared__ float t32[32 * 256];   // 32 KB
    const int tid = threadIdx.x;
    const int wv = tid >> 6, l = tid & 63;
    const int p0 = blockIdx.x * 32;
    const int n = p0 >> 10, hw0 = p0 & 1023;

    // ---- metadata prefetch (independent of staging) ----
    const int pl = tid >> 3, slot = tid & 7;
    const int p = p0 + pl;
    const int count = candCnt[p];
    const int c0raw = candC[(size_t)p * CAND_CAP + slot];
    const float da0 = candD[(size_t)p * CAND_CAP + slot];

    // ---- stage z tile [32 hw][256 k] fp32, coalesced, b128 LDS writes ----
    const int row = l & 31;
    const int xmr = (row & 7) * 4;
    #pragma unroll
    for (int i = 0; i < 8; ++i) {
        const int k4 = i * 32 + wv * 8 + (l >> 5) * 4;
        const size_t zb = ((size_t)(n * 256 + k4) << 10) + hw0 + row;
        float4 v;
        v.x = z[zb];
        v.y = z[zb + 1024];
        v.z = z[zb + 2048];
        v.w = z[zb + 3072];
        *(float4*)&t32[row * 256 + (k4 ^ xmr)] = v;
    }

    // ---- viability filter (registers + shuffles only) ----
    bool need;                // position requires exact dots
    float thr = 0.f;
    if (count <= CAND_CAP) {
        const int nr = (count + 7) >> 3;
        float m = (slot < count) ? da0 : FLT_MAX;
        for (int rr = 1; rr < nr; ++rr) {
            const int s = rr * 8 + slot;
            if (s < count) m = fminf(m, candD[(size_t)p * CAND_CAP + s]);
        }
        #pragma unroll
        for (int off = 1; off < 8; off <<= 1) m = fminf(m, __shfl_xor(m, off));
        thr = m + EPS_SCREEN;

        int V;
        int soleC = N_CODES;
        {
            const bool v0 = (slot < count) && (da0 <= thr);
            const unsigned long long mask = __ballot(v0);
            V = __popcll((mask >> ((l >> 3) * 8)) & 0xFFull);
            if (v0) soleC = c0raw;
        }
        for (int rr = 1; rr < nr; ++rr) {
            const int s = rr * 8 + slot;
            bool vs = false;
            if (s < count) {
                vs = (candD[(size_t)p * CAND_CAP + s] <= thr);
                if (vs && soleC == N_CODES) soleC = candC[(size_t)p * CAND_CAP + s];
            }
            const unsigned long long mask = __ballot(vs);
            V += __popcll((mask >> ((l >> 3) * 8)) & 0xFFull);
        }
        if (V == 1 && soleC != N_CODES) idx_out[p] = (float)soleC;
        need = (V >= 2);
    } else {
        need = true;   // overflow: full sweep below
    }

    __syncthreads();   // z tile ready

    if (!need) return;   // uniform across each 8-lane position group

    const float* zrow = &t32[pl * 256];
    const int xm = (pl & 7) * 4;

    // ---- zsq: numpy pairwise 128+128, 8 accumulators (exact k1 order) ----
    float halfv[2];
    #pragma unroll
    for (int h = 0; h < 2; ++h) {
        float r[8];
        {
            const f32x4 a = *(const f32x4*)&zrow[(h * 128) ^ xm];
            const f32x4 b = *(const f32x4*)&zrow[(h * 128 + 4) ^ xm];
            #pragma unroll
            for (int j = 0; j < 4; ++j) { r[j] = sq_sep(a[j]); r[4 + j] = sq_sep(b[j]); }
        }
        for (int i = 8; i < 128; i += 8) {
            const f32x4 a = *(const f32x4*)&zrow[(h * 128 + i) ^ xm];
            const f32x4 b = *(const f32x4*)&zrow[(h * 128 + i + 4) ^ xm];
            #pragma unroll
            for (int j = 0; j < 4; ++j) { r[j] += sq_sep(a[j]); r[4 + j] += sq_sep(b[j]); }
        }
        halfv[h] = ((r[0] + r[1]) + (r[2] + r[3])) + ((r[4] + r[5]) + (r[6] + r[7]));
    }
    const float zsv = halfv[0] + halfv[1];

#define DOT_CHAIN(wb_, dot_) do {                                              \
    _Pragma("unroll")                                                          \
    for (int kb = 0; kb < 256; kb += 8) {                                      \
        const f32x4 za = *(const f32x4*)&zrow[kb ^ xm];                        \
        const f32x4 zb4 = *(const f32x4*)&zrow[(kb + 4) ^ xm];                 \
        const float4 wa = *(const float4*)&(wb_)[kb];                          \
        const float4 wc = *(const float4*)&(wb_)[kb + 4];                      \
        dot_ = __builtin_fmaf(za[0], wa.x, dot_);                              \
        dot_ = __builtin_fmaf(za[1], wa.y, dot_);                              \
        dot_ = __builtin_fmaf(za[2], wa.z, dot_);                              \
        dot_ = __builtin_fmaf(za[3], wa.w, dot_);                              \
        dot_ = __builtin_fmaf(zb4[0], wc.x, dot_);                             \
        dot_ = __builtin_fmaf(zb4[1], wc.y, dot_);                             \
        dot_ = __builtin_fmaf(zb4[2], wc.z, dot_);                             \
        dot_ = __builtin_fmaf(zb4[3], wc.w, dot_);                             \
    }                                                                          \
} while (0)

    float bd = FLT_MAX;
    int bc = N_CODES;

    if (count <= CAND_CAP) {
        const int nr = (count + 7) >> 3;
        for (int rr = 0; rr < nr; ++rr) {
            const int s = rr * 8 + slot;
            int c; float das;
            if (rr == 0) { c = c0raw; das = da0; }
            else if (s < count) {
                c = candC[(size_t)p * CAND_CAP + s];
                das = candD[(size_t)p * CAND_CAP + s];
            } else { c = N_CODES; das = FLT_MAX; }
            if (s < count && das <= thr) {        // viable only
                const float* wb = wemb + (size_t)c * 256;
                float dot = 0.f;
                DOT_CHAIN(wb, dot);
                const float d = __builtin_fmaf(-2.f, dot, zsv) + wsq[c];
                if (d < bd || (d == bd && c < bc)) { bd = d; bc = c; }
            }
        }
    } else {
        for (int rr = 0; rr < 128; ++rr) {
            const int c = rr * 8 + slot;
            const float* wb = wemb + (size_t)c * 256;
            float dot = 0.f;
            DOT_CHAIN(wb, dot);
            const float d = __builtin_fmaf(-2.f, dot, zsv) + wsq[c];
            if (d < bd || (d == bd && c < bc)) { bd = d; bc = c; }
        }
    }
#undef DOT_CHAIN

    // lex-min (d, c) across the 8 slots of this position
    #pragma unroll
    for (int off = 1; off < 8; off <<= 1) {
        const float od = __shfl_xor(bd, off);
        const int   oi = __shfl_xor(bc, off);
        if (od < bd || (od == bd && oi < bc)) { bd = od; bc = oi; }
    }
    if (slot == 0) idx_out[p] = (float)bc;
}

// ---------------------------------------------------------------------------
// k3: gather + straight-through. Block = fixed (n, c); Wt column staged
// coalesced into LDS. UNCHANGED from validated R10.
// ---------------------------------------------------------------------------
__global__ void k3_gather(const float* __restrict__ z, const float* __restrict__ wtf,
                          const float* __restrict__ idxf,
                          float* __restrict__ out0, float* __restrict__ out1) {
    __shared__ float wcol[1024];
    const int tid = threadIdx.x;
    const int b = blockIdx.x;              // 8192 = 32 n x 256 c
    const int c = b & 255, n = b >> 8;
    *(float4*)&wcol[tid * 4] = *(const float4*)&wtf[(size_t)c * 1024 + tid * 4];
    __syncthreads();

    const size_t zo = (((size_t)(n * 256 + c)) << 10) + tid * 4;
    const float4 zv = *(const float4*)&z[zo];
    const float4 iv = *(const float4*)&idxf[n * 1024 + tid * 4];
    float4 qv, st;
    qv.x = wcol[(int)iv.x]; st.x = (qv.x - zv.x) + zv.x;
    qv.y = wcol[(int)iv.y]; st.y = (qv.y - zv.y) + zv.y;
    qv.z = wcol[(int)iv.z]; st.z = (qv.z - zv.z) + zv.z;
    qv.w = wcol[(int)iv.w]; st.w = (qv.w - zv.w) + zv.w;
    *(float4*)&out0[zo] = qv;
    *(float4*)&out1[zo] = st;
}

extern "C" void kernel_launch(void* const* d_in, const int* in_sizes, int n_in,
                              void* d_out, int out_size, void* d_ws, size_t ws_size,
                              hipStream_t stream) {
    const float* z = (const float*)d_in[0];
    const float* wemb = (const float*)d_in[1];
    float* out = (float*)d_out;
    float* out0 = out;                       // quantized (final)
    float* out1 = out + Q_ELEMS;             // straight_through (final)
    float* oidx = out + 2 * Q_ELEMS;         // indices-as-float (final)
    // big scratch inside d_out (all consumed before k3 overwrites):
    unsigned short* zhi = (unsigned short*)out0;                  // 16 MB  [0..4M floats)
    unsigned short* candC = (unsigned short*)(out0 + 4194304);    // 4 MB   [4M..5M floats)
    float* candD = out0 + 5242880;                                // 8 MB   [5M..7M floats)
    int* candCnt = (int*)(out0 + 7340032);                        // 128 KB [7M..7.03M)
    unsigned short* whi = (unsigned short*)out1;                  // 512 KB (out1 head)
    // d_ws scratch (~1.05 MB):
    float* wsq = (float*)d_ws;                // 1024 f32
    float* wtf = (float*)d_ws + 1024;         // 262144 f32 (Wt, exact f32)

    k0_prelude<<<836, 256, 0, stream>>>(z, wemb, wtf, whi, zhi, wsq, candCnt);
    k2s_screen<<<1024, 256, 0, stream>>>(zhi, whi, wsq, candC, candD, candCnt);
    k2r_rescore<<<P_TOTAL / 32, 256, 0, stream>>>(z, wemb, wsq, candC, candD, candCnt, oidx);
    k3_gather<<<8192, 256, 0, stream>>>(z, wtf, oidx, out0, out1);
}